// Round 1
// baseline (4032.531 us; speedup 1.0000x reference)
//
#include <hip/hip_runtime.h>

#define TT 1024
#define DD 768
#define FFD 3072
#define NH 12
#define NL 12
#define HDIM 64
#define VOC 50257
#define BT 2048  // B*T

typedef __attribute__((ext_vector_type(8))) __bf16 bf16x8;
typedef __attribute__((ext_vector_type(4))) float f32x4;
typedef unsigned short u16;

static __device__ __forceinline__ u16 f2bf(float f) {
  unsigned int u = __float_as_uint(f);
  u += 0x7FFF + ((u >> 16) & 1);  // round-to-nearest-even
  return (u16)(u >> 16);
}

// ---------------------------------------------------------------- converts
__global__ __launch_bounds__(256) void transpose_convert(
    const float* __restrict__ in, u16* __restrict__ out, int R, int C) {
  __shared__ float tile[32][33];
  const long long zo = (long long)blockIdx.z * R * C;
  const int c0 = blockIdx.x * 32, r0 = blockIdx.y * 32;
  const int tx = threadIdx.x & 31, ty = threadIdx.x >> 5;
#pragma unroll
  for (int i = 0; i < 32; i += 8)
    tile[ty + i][tx] = in[zo + (long long)(r0 + ty + i) * C + c0 + tx];
  __syncthreads();
#pragma unroll
  for (int i = 0; i < 32; i += 8)
    out[zo + (long long)(c0 + ty + i) * R + r0 + tx] = f2bf(tile[tx][ty + i]);
}

__global__ void convert_bf16(const float* __restrict__ in, u16* __restrict__ out,
                             long long n) {
  long long i = (long long)blockIdx.x * 256 + threadIdx.x;
  const long long stride = (long long)gridDim.x * 256;
  for (; i < n; i += stride) out[i] = f2bf(in[i]);
}

// ---------------------------------------------------------------- embed
__global__ __launch_bounds__(256) void embed_kernel(
    const int* __restrict__ tokens, const float* __restrict__ tokE,
    const float* __restrict__ posE, float* __restrict__ x) {
  const int row = blockIdx.x;        // b*1024 + t
  const int t = row & (TT - 1);
  const int tok = tokens[row];
  const int tid = threadIdx.x;
#pragma unroll
  for (int c = 0; c < 3; ++c) {
    int d = tid + c * 256;
    x[(long long)row * DD + d] = tokE[(long long)tok * DD + d] + posE[(long long)t * DD + d];
  }
}

// ---------------------------------------------------------------- layernorm
__global__ __launch_bounds__(256) void layernorm_bf16(
    const float* __restrict__ x, const float* __restrict__ w,
    const float* __restrict__ b, u16* __restrict__ out) {
  const int row = blockIdx.x;
  const float* xr = x + (long long)row * DD;
  const int tid = threadIdx.x;
  float v[3];
  float s = 0.f, s2 = 0.f;
#pragma unroll
  for (int c = 0; c < 3; ++c) {
    float t = xr[tid + c * 256];
    v[c] = t; s += t; s2 += t * t;
  }
  for (int off = 32; off; off >>= 1) {
    s += __shfl_down(s, off, 64);
    s2 += __shfl_down(s2, off, 64);
  }
  __shared__ float rs[8];
  if ((tid & 63) == 0) { rs[tid >> 6] = s; rs[4 + (tid >> 6)] = s2; }
  __syncthreads();
  s = rs[0] + rs[1] + rs[2] + rs[3];
  s2 = rs[4] + rs[5] + rs[6] + rs[7];
  const float mu = s * (1.0f / DD);
  const float var = s2 * (1.0f / DD) - mu * mu;
  const float inv = rsqrtf(var + 1e-5f);
  u16* o = out + (long long)row * DD;
#pragma unroll
  for (int c = 0; c < 3; ++c) {
    int d = tid + c * 256;
    o[d] = f2bf((v[c] - mu) * inv * w[d] + b[d]);
  }
}

// ---------------------------------------------------------------- V transpose
// vT[(b*NH+h)*64 + d][t] = qkv[b*1024+t][1536 + h*64 + d]
__global__ __launch_bounds__(256) void transpose_v(const u16* __restrict__ qkv,
                                                   u16* __restrict__ vT) {
  __shared__ u16 tile[64][65];
  const int z = blockIdx.y;
  const int b = z / NH, h = z - (z / NH) * NH;
  const int t0 = blockIdx.x * 64;
  const int tx = threadIdx.x & 63, ty = threadIdx.x >> 6;
  const u16* src = qkv + (long long)(b * TT + t0) * 2304 + 1536 + h * 64;
#pragma unroll
  for (int i = 0; i < 64; i += 4)
    tile[ty + i][tx] = src[(long long)(ty + i) * 2304 + tx];
  __syncthreads();
  u16* dst = vT + (long long)z * 64 * 1024 + t0;
#pragma unroll
  for (int i = 0; i < 64; i += 4)
    dst[(long long)(ty + i) * 1024 + tx] = tile[tx][ty + i];
}

// ---------------------------------------------------------------- softmax
__global__ __launch_bounds__(256) void softmax_causal(const float* __restrict__ S,
                                                      u16* __restrict__ P) {
  const int row = blockIdx.x;  // query index 0..1023
  const int z = blockIdx.y;    // 0..23
  const float* s = S + ((long long)z * 1024 + row) * 1024;
  u16* p = P + ((long long)z * 1024 + row) * 1024;
  const int tid = threadIdx.x;
  float vals[4];
  float m = -1e30f;
#pragma unroll
  for (int c = 0; c < 4; ++c) {
    int j = tid + c * 256;
    float v = (j <= row) ? s[j] * 0.125f : -1e30f;
    vals[c] = v;
    m = fmaxf(m, v);
  }
  for (int off = 32; off; off >>= 1) m = fmaxf(m, __shfl_down(m, off, 64));
  __shared__ float red[8];
  if ((tid & 63) == 0) red[tid >> 6] = m;
  __syncthreads();
  m = fmaxf(fmaxf(red[0], red[1]), fmaxf(red[2], red[3]));
  float sum = 0.f;
#pragma unroll
  for (int c = 0; c < 4; ++c) {
    float e = __expf(vals[c] - m);  // masked -> exp(-huge) = 0
    vals[c] = e;
    sum += e;
  }
  for (int off = 32; off; off >>= 1) sum += __shfl_down(sum, off, 64);
  __syncthreads();
  if ((tid & 63) == 0) red[4 + (tid >> 6)] = sum;
  __syncthreads();
  sum = red[4] + red[5] + red[6] + red[7];
  const float inv = 1.0f / sum;
#pragma unroll
  for (int c = 0; c < 4; ++c) p[tid + c * 256] = f2bf(vals[c] * inv);
}

// ---------------------------------------------------------------- GEMM (NT)
// C[z][m][n] = sum_k A[z][m][k] * B[z][n][k]  (+ epilogue)
// z decomposed as zb = z/Hdiv, zh = z%Hdiv; per-operand offsets zb*Hi + zh*Lo.
enum { EPI_F32 = 0, EPI_BF16_BIAS = 1, EPI_BF16_BIAS_GELU = 2, EPI_F32_BIAS_RES = 3, EPI_BF16 = 4 };

#define LP 40  // LDS row pitch in bf16 elems (32 + 8 pad -> 80B rows, 2-way bank alias = free)

template <int EPI>
__global__ __launch_bounds__(256, 2) void gemm_nt(
    const u16* __restrict__ A, const u16* __restrict__ Bm,
    const float* __restrict__ bias, const float* __restrict__ resid,
    void* __restrict__ Cout, int M, int N, int K, int lda, int ldb, int ldc,
    long long aHi, long long aLo, long long bHi, long long bLo,
    long long cHi, long long cLo, int Hdiv) {
  __shared__ __align__(16) u16 As[128 * LP];
  __shared__ __align__(16) u16 Bs[128 * LP];
  const int z = blockIdx.z;
  const int zb = z / Hdiv, zh = z - zb * Hdiv;
  const u16* Ab = A + zb * aHi + zh * aLo;
  const u16* Bb = Bm + zb * bHi + zh * bLo;
  const long long cOff = (long long)zb * cHi + (long long)zh * cLo;

  const int m0 = blockIdx.y * 128;
  const int n0 = blockIdx.x * 128;
  const int tid = threadIdx.x;
  const int lane = tid & 63;
  const int wave = tid >> 6;
  const int wm = (wave >> 1) * 64;
  const int wn = (wave & 1) * 64;
  const int mf = lane & 15;
  const int quad = lane >> 4;

  // staging: 2 threads per row, 16 bf16 (32B) each
  const int srow = tid >> 1;
  const int scol = (tid & 1) * 16;
  const int arow = m0 + srow;                      // M is always a multiple of 128 here
  int brow = n0 + srow; if (brow >= N) brow = N - 1;  // clamp for lm_head tail
  const u16* ap = Ab + (long long)arow * lda + scol;
  const u16* bp = Bb + (long long)brow * ldb + scol;
  u16* asw = &As[srow * LP + scol];
  u16* bsw = &Bs[srow * LP + scol];

  f32x4 acc[4][4] = {};

  for (int k0 = 0; k0 < K; k0 += 32) {
    uint4 av0 = *(const uint4*)(ap + k0);
    uint4 av1 = *(const uint4*)(ap + k0 + 8);
    uint4 bv0 = *(const uint4*)(bp + k0);
    uint4 bv1 = *(const uint4*)(bp + k0 + 8);
    __syncthreads();
    *(uint4*)asw = av0;
    *(uint4*)(asw + 8) = av1;
    *(uint4*)bsw = bv0;
    *(uint4*)(bsw + 8) = bv1;
    __syncthreads();
    bf16x8 afr[4], bfr[4];
#pragma unroll
    for (int i = 0; i < 4; ++i)
      afr[i] = *(const bf16x8*)(&As[(wm + i * 16 + mf) * LP + quad * 8]);
#pragma unroll
    for (int j = 0; j < 4; ++j)
      bfr[j] = *(const bf16x8*)(&Bs[(wn + j * 16 + mf) * LP + quad * 8]);
#pragma unroll
    for (int i = 0; i < 4; ++i)
#pragma unroll
      for (int j = 0; j < 4; ++j)
        acc[i][j] = __builtin_amdgcn_mfma_f32_16x16x32_bf16(afr[i], bfr[j], acc[i][j], 0, 0, 0);
  }

#pragma unroll
  for (int j = 0; j < 4; ++j) {
    const int col = n0 + wn + j * 16 + mf;
    if (col >= N) continue;
    const float bv = (EPI == EPI_BF16_BIAS || EPI == EPI_BF16_BIAS_GELU || EPI == EPI_F32_BIAS_RES)
                         ? bias[col] : 0.0f;
#pragma unroll
    for (int i = 0; i < 4; ++i) {
#pragma unroll
      for (int r = 0; r < 4; ++r) {
        const int row = m0 + wm + i * 16 + quad * 4 + r;
        float v = acc[i][j][r] + bv;
        if (EPI == EPI_BF16_BIAS_GELU) {
          float u = v + 0.044715f * v * v * v;
          v = 0.5f * v * (1.0f + tanhf(0.7978845608028654f * u));
        }
        const long long ci = cOff + (long long)row * ldc + col;
        if (EPI == EPI_F32_BIAS_RES) {
          ((float*)Cout)[ci] = resid[(long long)row * ldc + col] + v;
        } else if (EPI == EPI_F32) {
          ((float*)Cout)[ci] = v;
        } else {
          ((u16*)Cout)[ci] = f2bf(v);
        }
      }
    }
  }
}

// ---------------------------------------------------------------- launch
extern "C" void kernel_launch(void* const* d_in, const int* in_sizes, int n_in,
                              void* d_out, int out_size, void* d_ws, size_t ws_size,
                              hipStream_t stream) {
  const int* tokens      = (const int*)d_in[0];
  const float* tok_embed = (const float*)d_in[1];
  const float* pos_embed = (const float*)d_in[2];
  const float* qkv_w     = (const float*)d_in[3];
  const float* qkv_b     = (const float*)d_in[4];
  const float* proj_w    = (const float*)d_in[5];
  const float* proj_b    = (const float*)d_in[6];
  const float* ln1_w     = (const float*)d_in[7];
  const float* ln1_b     = (const float*)d_in[8];
  const float* ln2_w     = (const float*)d_in[9];
  const float* ln2_b     = (const float*)d_in[10];
  const float* fc1_w     = (const float*)d_in[11];
  const float* fc1_b     = (const float*)d_in[12];
  const float* fc2_w     = (const float*)d_in[13];
  const float* fc2_b     = (const float*)d_in[14];
  const float* lnf_w     = (const float*)d_in[15];
  const float* lnf_b     = (const float*)d_in[16];

  if (ws_size < 440u * 1024u * 1024u) return;  // needs ~439 MB scratch

  char* p = (char*)d_ws;
  auto alloc = [&](size_t bytes) {
    void* r = (void*)p;
    p += (bytes + 255) & ~(size_t)255;
    return r;
  };
  u16* wq   = (u16*)alloc((size_t)NL * 2304 * 768 * 2);  // qkv_w^T  [L][2304][768]
  u16* wp   = (u16*)alloc((size_t)NL * 768 * 768 * 2);   // proj_w^T [L][768][768]
  u16* w1   = (u16*)alloc((size_t)NL * 3072 * 768 * 2);  // fc1_w^T  [L][3072][768]
  u16* w2   = (u16*)alloc((size_t)NL * 768 * 3072 * 2);  // fc2_w^T  [L][768][3072]
  u16* te   = (u16*)alloc((size_t)VOC * 768 * 2);        // tok_embed bf16 [V][768]
  float* x  = (float*)alloc((size_t)BT * 768 * 4);       // residual stream fp32
  u16* hbuf = (u16*)alloc((size_t)BT * 768 * 2);         // LN output bf16
  u16* qkv  = (u16*)alloc((size_t)BT * 2304 * 2);
  u16* vT   = (u16*)alloc((size_t)24 * 64 * 1024 * 2);   // [b,h][64][1024]
  float* sc = (float*)alloc((size_t)24 * 1024 * 1024 * 4);
  u16* P    = (u16*)alloc((size_t)24 * 1024 * 1024 * 2);
  u16* attn = (u16*)alloc((size_t)BT * 768 * 2);
  u16* ff   = (u16*)alloc((size_t)BT * 3072 * 2);
  u16* xf   = (u16*)alloc((size_t)BT * 768 * 2);

  // weight conversion (per call; ws is re-poisoned before every timed launch)
  transpose_convert<<<dim3(2304 / 32, 768 / 32, NL), 256, 0, stream>>>(qkv_w, wq, 768, 2304);
  transpose_convert<<<dim3(768 / 32, 768 / 32, NL), 256, 0, stream>>>(proj_w, wp, 768, 768);
  transpose_convert<<<dim3(3072 / 32, 768 / 32, NL), 256, 0, stream>>>(fc1_w, w1, 768, 3072);
  transpose_convert<<<dim3(768 / 32, 3072 / 32, NL), 256, 0, stream>>>(fc2_w, w2, 3072, 768);
  convert_bf16<<<4096, 256, 0, stream>>>(tok_embed, te, (long long)VOC * 768);
  embed_kernel<<<BT, 256, 0, stream>>>(tokens, tok_embed, pos_embed, x);

  const long long QKV_B = (long long)TT * 2304;  // per-batch stride in qkv

  for (int l = 0; l < NL; ++l) {
    layernorm_bf16<<<BT, 256, 0, stream>>>(x, ln1_w + l * 768, ln1_b + l * 768, hbuf);
    gemm_nt<EPI_BF16_BIAS><<<dim3(2304 / 128, BT / 128, 1), 256, 0, stream>>>(
        hbuf, wq + (size_t)l * 2304 * 768, qkv_b + l * 2304, nullptr, qkv,
        BT, 2304, 768, 768, 768, 2304, 0, 0, 0, 0, 0, 0, 1);
    transpose_v<<<dim3(16, 24), 256, 0, stream>>>(qkv, vT);
    // scores[z][q][k] = Q.K^T  (z = b*12+h)
    gemm_nt<EPI_F32><<<dim3(8, 8, 24), 256, 0, stream>>>(
        qkv, qkv + 768, nullptr, nullptr, sc,
        1024, 1024, 64, 2304, 2304, 1024,
        QKV_B, 64, QKV_B, 64,
        (long long)12 * 1024 * 1024, (long long)1024 * 1024, NH);
    softmax_causal<<<dim3(1024, 24), 256, 0, stream>>>(sc, P);
    // attn[b*1024+t][h*64+d] = P @ V
    gemm_nt<EPI_BF16><<<dim3(1, 8, 24), 256, 0, stream>>>(
        P, vT, nullptr, nullptr, attn,
        1024, 64, 1024, 1024, 1024, 768,
        (long long)12 * 1024 * 1024, (long long)1024 * 1024,
        (long long)12 * 64 * 1024, (long long)64 * 1024,
        (long long)TT * 768, 64, NH);
    gemm_nt<EPI_F32_BIAS_RES><<<dim3(768 / 128, BT / 128, 1), 256, 0, stream>>>(
        attn, wp + (size_t)l * 768 * 768, proj_b + l * 768, x, x,
        BT, 768, 768, 768, 768, 768, 0, 0, 0, 0, 0, 0, 1);
    layernorm_bf16<<<BT, 256, 0, stream>>>(x, ln2_w + l * 768, ln2_b + l * 768, hbuf);
    gemm_nt<EPI_BF16_BIAS_GELU><<<dim3(3072 / 128, BT / 128, 1), 256, 0, stream>>>(
        hbuf, w1 + (size_t)l * 3072 * 768, fc1_b + l * 3072, nullptr, ff,
        BT, 3072, 768, 768, 768, 3072, 0, 0, 0, 0, 0, 0, 1);
    gemm_nt<EPI_F32_BIAS_RES><<<dim3(768 / 128, BT / 128, 1), 256, 0, stream>>>(
        ff, w2 + (size_t)l * 768 * 3072, fc2_b + l * 768, x, x,
        BT, 768, 3072, 3072, 3072, 768, 0, 0, 0, 0, 0, 0, 1);
  }
  layernorm_bf16<<<BT, 256, 0, stream>>>(x, lnf_w, lnf_b, xf);
  gemm_nt<EPI_F32><<<dim3((VOC + 127) / 128, BT / 128, 1), 256, 0, stream>>>(
      xf, te, nullptr, nullptr, (float*)d_out,
      BT, VOC, 768, 768, 768, VOC, 0, 0, 0, 0, 0, 0, 1);
}